// Round 4
// baseline (198.066 us; speedup 1.0000x reference)
//
#include <hip/hip_runtime.h>
#include <stdint.h>

typedef short short8 __attribute__((ext_vector_type(8)));
typedef float f32x4 __attribute__((ext_vector_type(4)));

#define TILE 128          // A-tile rows per block (and K_MM reg-tile rows)
#define BCOLS 64          // B cols per m-iteration (2 x 16-col groups per wave)

__device__ __forceinline__ unsigned short f32_to_bf16(float f) {
    uint32_t u = __builtin_bit_cast(uint32_t, f);
    u += 0x7FFFu + ((u >> 16) & 1u);   // RNE; data has no NaNs
    return (unsigned short)(u >> 16);
}
__device__ __forceinline__ float bf16_to_f32(unsigned short h) {
    return __builtin_bit_cast(float, (uint32_t)h << 16);
}

// Prep: centers fp32 -> bf16 in MFMA fragment layout, cw[m] = {||c||^2 * q, alpha[m]},
// and zero the accumulators (loss, reg, block counter).
// Fragment layout: element (row R, k) -> Bp[(R/16)*2048 + (k/8)*128 + (R%16)*8 + (k%8)]
__global__ void prep_kernel(const float* __restrict__ C,
                            const float* __restrict__ alpha,
                            const float* __restrict__ sigma,
                            unsigned short* __restrict__ Bp,
                            float2* __restrict__ cw,
                            float* __restrict__ acc)
{
    const int t = threadIdx.x;
    const int g = blockIdx.x;          // 16-row group
    const int r = t >> 4;              // row within group
    const int c16 = t & 15;            // 8-elem k-chunk
    const int R = g * 16 + r;

    if (g == 0 && t == 0) {
        acc[0] = 0.f; acc[1] = 0.f;
        ((unsigned int*)acc)[2] = 0u;
    }

    const float4* src = (const float4*)(C + (size_t)R * 128 + c16 * 8);
    float4 va = src[0], vb = src[1];
    unsigned short h[8];
    h[0] = f32_to_bf16(va.x); h[1] = f32_to_bf16(va.y);
    h[2] = f32_to_bf16(va.z); h[3] = f32_to_bf16(va.w);
    h[4] = f32_to_bf16(vb.x); h[5] = f32_to_bf16(vb.y);
    h[6] = f32_to_bf16(vb.z); h[7] = f32_to_bf16(vb.w);
    float ss = 0.f;
    #pragma unroll
    for (int k = 0; k < 8; ++k) {
        float f = bf16_to_f32(h[k]);
        ss = fmaf(f, f, ss);
    }
    uint4 pk;
    pk.x = (uint32_t)h[0] | ((uint32_t)h[1] << 16);
    pk.y = (uint32_t)h[2] | ((uint32_t)h[3] << 16);
    pk.z = (uint32_t)h[4] | ((uint32_t)h[5] << 16);
    pk.w = (uint32_t)h[6] | ((uint32_t)h[7] << 16);
    *reinterpret_cast<uint4*>(Bp + (size_t)g * 2048 + c16 * 128 + r * 8) = pk;

    ss += __shfl_xor(ss, 1);
    ss += __shfl_xor(ss, 2);
    ss += __shfl_xor(ss, 4);
    ss += __shfl_xor(ss, 8);
    if (c16 == 0) {
        float sig = sigma[0];
        float q = 0.7213475204444817f / (sig * sig);  // log2(e)/(2 sigma^2)
        cw[R] = make_float2(ss * q, alpha[R]);
    }
}

// Fused: blocks [0,nA) = preds + loss-sum; blocks [nA,nA+nMt) = K_MM regularizer.
// 512 threads = 8 waves in a 4(row)x2(col) grid; each wave owns 32 rows x 32
// cols of the 128x64 column tile.
//
// R5 change: BARRIER-FREE m-loop. Re-derived from R0/R2: per-BLOCK latency is
// ~73us in both (R0 113us = 1.56 rounds x 72; R2 76us = 1.04 x 73) -- wall
// time IS single-block latency, ~5500 cyc/iter vs ~1500 cyc of pipe work.
// The per-iteration __syncthreads (full vmcnt drain + 8-wave lockstep convoy)
// is the dominant stall, and more residency can never fix it. Bp is 524 KB =
// L2-resident per XCD (4MB), so LDS staging of B is pure overhead (m169):
// read B fragments straight from global (lane*16B coalesced dwordx4), delete
// the DMA + double buffer + ALL in-loop barriers. Waves run free; the
// compiler software-pipelines global loads across iterations (no barrier to
// drain vmcnt). L2 read traffic 4x (wave amplification) ~= 1.6 GB total
// ~45us at 34.5 TB/s, overlapped with ~36us of VALU work.
// (R3/R4 lessons kept: no asm scheduling pins; no LDS reads in the MFMA
// C-dependency chain; rowterm stays in registers. When VGPR_Count collapses
// below ~50 the compiler has de-scheduled -- that is a bug signature.)
__global__ __launch_bounds__(512, 4)
void fused_kernel(const float* __restrict__ X, int N,
                  const float* __restrict__ Yv,
                  const unsigned short* __restrict__ Bp,
                  const float2* __restrict__ cw,
                  const float* __restrict__ alpha,
                  const float* __restrict__ sigma,
                  const float* __restrict__ penalty,
                  int nA, int nMt, int nBlk,
                  float* __restrict__ preds_out,
                  float* __restrict__ out0,
                  float* __restrict__ acc)   // [0]=loss,[1]=reg,[2]=counter
{
    __shared__ __align__(16) unsigned short ldsA[16384];  // 32 KB A-staging only
    __shared__ float a2p[TILE][4];
    __shared__ float predbuf[TILE][2];

    const int t    = threadIdx.x;
    const int lane = t & 63;
    const int wid  = t >> 6;     // 0..7
    const int wr   = wid >> 1;   // 0..3: rows wr*32 .. +32
    const int wc   = wid & 1;    // 0..1: cols wc*32 .. +32
    const int l15  = lane & 15;
    const int quad = lane >> 4;

    const float sig = sigma[0];
    const float q  = 0.7213475204444817f / (sig * sig);
    const float q2 = 2.0f * q;

    const bool regmode = (int)blockIdx.x >= nA;
    int rowbase;
    float rowterm[2][4];
    short8 a[8];   // A fragments, tile-invariant: a[i*4+kk], i in {0,1}

    if (!regmode) {
        rowbase = blockIdx.x * TILE;
        // stage X tile into fragment-layout LDS; each thread converts a
        // quarter-row (32 elems)
        const int r_  = t >> 2;
        const int qtr = t & 3;
        const int grow = rowbase + r_;
        unsigned short* dstbase = &ldsA[0] + (r_ >> 4) * 2048 + (r_ & 15) * 8;
        float ss = 0.f;
        if (grow < N) {
            const float4* src = (const float4*)(X + (size_t)grow * 128 + qtr * 32);
            #pragma unroll
            for (int c = 0; c < 4; ++c) {
                float4 va = src[2 * c], vb = src[2 * c + 1];
                unsigned short h0 = f32_to_bf16(va.x), h1 = f32_to_bf16(va.y);
                unsigned short h2 = f32_to_bf16(va.z), h3 = f32_to_bf16(va.w);
                unsigned short h4 = f32_to_bf16(vb.x), h5 = f32_to_bf16(vb.y);
                unsigned short h6 = f32_to_bf16(vb.z), h7 = f32_to_bf16(vb.w);
                float f0 = bf16_to_f32(h0), f1 = bf16_to_f32(h1);
                float f2 = bf16_to_f32(h2), f3 = bf16_to_f32(h3);
                float f4 = bf16_to_f32(h4), f5 = bf16_to_f32(h5);
                float f6 = bf16_to_f32(h6), f7 = bf16_to_f32(h7);
                ss = fmaf(f0, f0, ss); ss = fmaf(f1, f1, ss);
                ss = fmaf(f2, f2, ss); ss = fmaf(f3, f3, ss);
                ss = fmaf(f4, f4, ss); ss = fmaf(f5, f5, ss);
                ss = fmaf(f6, f6, ss); ss = fmaf(f7, f7, ss);
                uint4 pk;
                pk.x = (uint32_t)h0 | ((uint32_t)h1 << 16);
                pk.y = (uint32_t)h2 | ((uint32_t)h3 << 16);
                pk.z = (uint32_t)h4 | ((uint32_t)h5 << 16);
                pk.w = (uint32_t)h6 | ((uint32_t)h7 << 16);
                *reinterpret_cast<uint4*>(dstbase + (qtr * 4 + c) * 128) = pk;
            }
        } else {
            uint4 z; z.x = z.y = z.z = z.w = 0u;
            #pragma unroll
            for (int c = 0; c < 4; ++c)
                *reinterpret_cast<uint4*>(dstbase + (qtr * 4 + c) * 128) = z;
        }
        a2p[r_][qtr] = ss;
        __syncthreads();
        #pragma unroll
        for (int i = 0; i < 2; ++i)
            #pragma unroll
            for (int r = 0; r < 4; ++r) {
                int rl = wr * 32 + i * 16 + quad * 4 + r;
                rowterm[i][r] = (a2p[rl][0] + a2p[rl][1] + a2p[rl][2] + a2p[rl][3]) * q;
            }
        // hoist A fragments: 8 ds_read_b128, once for the whole kernel.
        // Nothing overwrites ldsA afterwards -> no second barrier needed.
        const unsigned short* aLds = &ldsA[0] + (size_t)(wr * 2) * 2048 + lane * 8;
        #pragma unroll
        for (int i = 0; i < 2; ++i)
            #pragma unroll
            for (int kk = 0; kk < 4; ++kk)
                a[i * 4 + kk] = *reinterpret_cast<const short8*>(aLds + (size_t)i * 2048 + kk * 512);
    } else {
        const int b2 = (int)blockIdx.x - nA;
        rowbase = b2 * TILE;
        const unsigned short* aG = Bp + (size_t)(b2 * 8 + wr * 2) * 2048 + lane * 8;
        #pragma unroll
        for (int i = 0; i < 2; ++i)
            #pragma unroll
            for (int kk = 0; kk < 4; ++kk)
                a[i * 4 + kk] = *reinterpret_cast<const short8*>(aG + (size_t)i * 2048 + kk * 512);
        #pragma unroll
        for (int i = 0; i < 2; ++i)
            #pragma unroll
            for (int r = 0; r < 4; ++r)
                rowterm[i][r] = cw[rowbase + wr * 32 + i * 16 + quad * 4 + r].x;
    }

    float srow[2][4] = {};
    const float2* cwb = cw + wc * 32 + l15;
    // wave's B base: 16-col group (mt*4 + wc*2), fragment offset lane*8
    const unsigned short* bbase = Bp + (size_t)(wc * 2) * 2048 + lane * 8;

    // Barrier-free m-loop: B fragments straight from global (L2-resident).
    for (int mt = 0; mt < nMt; ++mt) {
        float2 cj[2];
        #pragma unroll
        for (int j = 0; j < 2; ++j) cj[j] = cwb[(size_t)mt * 64 + j * 16];

        const unsigned short* bg = bbase + (size_t)mt * 8192;
        #pragma unroll
        for (int j = 0; j < 2; ++j) {
            short8 b[4];
            #pragma unroll
            for (int kk = 0; kk < 4; ++kk)
                b[kk] = *reinterpret_cast<const short8*>(bg + (size_t)j * 2048 + kk * 512);

            f32x4 acc4[2];
            #pragma unroll
            for (int i = 0; i < 2; ++i) acc4[i] = (f32x4){0.f, 0.f, 0.f, 0.f};
            #pragma unroll
            for (int kk = 0; kk < 4; ++kk)
                #pragma unroll
                for (int i = 0; i < 2; ++i)
                    acc4[i] = __builtin_amdgcn_mfma_f32_16x16x32_bf16(
                        a[i * 4 + kk], b[kk], acc4[i], 0, 0, 0);

            // epilogue: u = 2q*dot - (q*x2 + q*c2) <= ~0 ; srow += exp2(u)*alpha
            #pragma unroll
            for (int i = 0; i < 2; ++i) {
                #pragma unroll
                for (int r = 0; r < 4; ++r) {
                    float u = fmaf(acc4[i][r], q2, -(rowterm[i][r] + cj[j].x));
                    float e = __builtin_amdgcn_exp2f(u);
                    srow[i][r] = fmaf(e, cj[j].y, srow[i][r]);
                }
            }
        }
    }

    // reduce srow over the 16 lanes sharing a row
    #pragma unroll
    for (int i = 0; i < 2; ++i) {
        #pragma unroll
        for (int r = 0; r < 4; ++r) {
            int rl = wr * 32 + i * 16 + quad * 4 + r;
            float v = srow[i][r];
            v += __shfl_xor(v, 1);
            v += __shfl_xor(v, 2);
            v += __shfl_xor(v, 4);
            v += __shfl_xor(v, 8);
            if (l15 == 0)
                predbuf[rl][wc] = v;
        }
    }
    __syncthreads();

    float contrib = 0.f;
    if (t < TILE) {
        int grow = rowbase + t;
        if (!regmode) {
            if (grow < N) {
                float pred = predbuf[t][0] + predbuf[t][1];
                preds_out[grow] = pred;
                float d = pred - Yv[grow];
                contrib = d * d;
            }
        } else {
            float pred = predbuf[t][0] + predbuf[t][1];
            contrib = alpha[grow] * pred;
        }
    }
    contrib += __shfl_xor(contrib, 1);
    contrib += __shfl_xor(contrib, 2);
    contrib += __shfl_xor(contrib, 4);
    contrib += __shfl_xor(contrib, 8);
    contrib += __shfl_xor(contrib, 16);
    contrib += __shfl_xor(contrib, 32);
    if (lane == 0 && wid < 2) atomicAdd(regmode ? (acc + 1) : (acc + 0), contrib);

    __syncthreads();   // all waves' atomics drained before counting
    if (t == 0) {
        __threadfence();
        unsigned int old = atomicAdd((unsigned int*)(acc + 2), 1u);
        if (old == (unsigned int)(nBlk - 1)) {
            float lv = atomicAdd(acc + 0, 0.0f);   // coherent read-back
            float rv = atomicAdd(acc + 1, 0.0f);
            out0[0] = lv / (float)N + __expf(-penalty[0]) * rv;
        }
    }
}

extern "C" void kernel_launch(void* const* d_in, const int* in_sizes, int n_in,
                              void* d_out, int out_size, void* d_ws, size_t ws_size,
                              hipStream_t stream) {
    const float* X       = (const float*)d_in[0];
    const float* Y       = (const float*)d_in[1];
    const float* centers = (const float*)d_in[2];
    const float* alpha   = (const float*)d_in[3];
    const float* sigma   = (const float*)d_in[4];
    const float* penalty = (const float*)d_in[5];
    float* out = (float*)d_out;

    const int N = in_sizes[1];   // Y is [N,1]
    const int M = in_sizes[3];   // alpha is [M,1]

    unsigned short* Bp = (unsigned short*)d_ws;                 // M*128 bf16 = M*256 B
    float2* cw = (float2*)((char*)d_ws + (size_t)M * 256);      // M*8 B
    float* acc = (float*)((char*)d_ws + (size_t)M * 264);       // loss, reg, counter

    prep_kernel<<<M / 16, 256, 0, stream>>>(centers, alpha, sigma, Bp, cw, acc);

    const int nA  = (N + TILE - 1) / TILE;
    const int nMt = M / BCOLS;            // 64-col B tiles
    const int nBlk = nA + M / TILE;
    fused_kernel<<<nBlk, 512, 0, stream>>>(X, N, Y, Bp, cw, alpha, sigma, penalty,
                                           nA, nMt, nBlk, out + 1, out, acc);
}

// Round 5
// 192.301 us; speedup vs baseline: 1.0300x; 1.0300x over previous
//
#include <hip/hip_runtime.h>
#include <stdint.h>

typedef short short8 __attribute__((ext_vector_type(8)));
typedef float f32x4 __attribute__((ext_vector_type(4)));

#define TILE 128          // A-tile rows per block (and K_MM reg-tile rows)
#define BCOLS 64          // B cols per m-iteration (2 x 16-col groups per wave)

__device__ __forceinline__ unsigned short f32_to_bf16(float f) {
    uint32_t u = __builtin_bit_cast(uint32_t, f);
    u += 0x7FFFu + ((u >> 16) & 1u);   // RNE; data has no NaNs
    return (unsigned short)(u >> 16);
}
__device__ __forceinline__ float bf16_to_f32(unsigned short h) {
    return __builtin_bit_cast(float, (uint32_t)h << 16);
}

// Prep: centers fp32 -> bf16 in MFMA fragment layout, cw[m] = {||c||^2 * q, alpha[m]},
// and zero the accumulators (loss, reg, block counter).
// Fragment layout: element (row R, k) -> Bp[(R/16)*2048 + (k/8)*128 + (R%16)*8 + (k%8)]
__global__ void prep_kernel(const float* __restrict__ C,
                            const float* __restrict__ alpha,
                            const float* __restrict__ sigma,
                            unsigned short* __restrict__ Bp,
                            float2* __restrict__ cw,
                            float* __restrict__ acc)
{
    const int t = threadIdx.x;
    const int g = blockIdx.x;          // 16-row group
    const int r = t >> 4;              // row within group
    const int c16 = t & 15;            // 8-elem k-chunk
    const int R = g * 16 + r;

    if (g == 0 && t == 0) {
        acc[0] = 0.f; acc[1] = 0.f;
        ((unsigned int*)acc)[2] = 0u;
    }

    const float4* src = (const float4*)(C + (size_t)R * 128 + c16 * 8);
    float4 va = src[0], vb = src[1];
    unsigned short h[8];
    h[0] = f32_to_bf16(va.x); h[1] = f32_to_bf16(va.y);
    h[2] = f32_to_bf16(va.z); h[3] = f32_to_bf16(va.w);
    h[4] = f32_to_bf16(vb.x); h[5] = f32_to_bf16(vb.y);
    h[6] = f32_to_bf16(vb.z); h[7] = f32_to_bf16(vb.w);
    float ss = 0.f;
    #pragma unroll
    for (int k = 0; k < 8; ++k) {
        float f = bf16_to_f32(h[k]);
        ss = fmaf(f, f, ss);
    }
    uint4 pk;
    pk.x = (uint32_t)h[0] | ((uint32_t)h[1] << 16);
    pk.y = (uint32_t)h[2] | ((uint32_t)h[3] << 16);
    pk.z = (uint32_t)h[4] | ((uint32_t)h[5] << 16);
    pk.w = (uint32_t)h[6] | ((uint32_t)h[7] << 16);
    *reinterpret_cast<uint4*>(Bp + (size_t)g * 2048 + c16 * 128 + r * 8) = pk;

    ss += __shfl_xor(ss, 1);
    ss += __shfl_xor(ss, 2);
    ss += __shfl_xor(ss, 4);
    ss += __shfl_xor(ss, 8);
    if (c16 == 0) {
        float sig = sigma[0];
        float q = 0.7213475204444817f / (sig * sig);  // log2(e)/(2 sigma^2)
        cw[R] = make_float2(ss * q, alpha[R]);
    }
}

// Fused: blocks [0,nA) = preds + loss-sum; blocks [nA,nA+nMt) = K_MM regularizer.
// 512 threads = 8 waves in a 4(row)x2(col) grid; each wave owns 32 rows x 32
// cols of the 128x64 column tile.
//
// R6: barrier-free m-loop (R5) + MANUAL register double-buffer for B.
// Evidence trail: R2 (LDS DMA dbuf + per-iter __syncthreads) = 76us, block
// latency ~73us dominated by barrier convoy; R5 (global-B, no prefetch) =
// 124us -- hipcc does NOT software-pipeline global loads across steps by
// itself (VGPR 52 = no prefetch regs, ~300cy L2 latency exposed per j-step).
// Fix: two-stage named reg buffer (bA/bB, static indices): each j-step
// issues the NEXT step's 4 dwordx4 loads, then computes from regs loaded one
// step earlier. The compiler's exact vmcnt FIFO counting leaves the 4 newest
// loads outstanding during compute (~250-300cy of MFMA+exp2 covers ~300cy L2
// latency). No barriers, no asm pins (R3 lesson), nothing on the MFMA
// C-chain (R4 lesson). Bp (524KB) is L2-resident; expected bounds: VALU ~32us,
// L2 BW (1.6GB @ 34.5TB/s) ~46us -> target ~55-65us fused.
__global__ __launch_bounds__(512, 4)
void fused_kernel(const float* __restrict__ X, int N,
                  const float* __restrict__ Yv,
                  const unsigned short* __restrict__ Bp,
                  const float2* __restrict__ cw,
                  const float* __restrict__ alpha,
                  const float* __restrict__ sigma,
                  const float* __restrict__ penalty,
                  int nA, int nMt, int nBlk,
                  float* __restrict__ preds_out,
                  float* __restrict__ out0,
                  float* __restrict__ acc)   // [0]=loss,[1]=reg,[2]=counter
{
    __shared__ __align__(16) unsigned short ldsA[16384];  // 32 KB A-staging only
    __shared__ float a2p[TILE][4];
    __shared__ float predbuf[TILE][2];

    const int t    = threadIdx.x;
    const int lane = t & 63;
    const int wid  = t >> 6;     // 0..7
    const int wr   = wid >> 1;   // 0..3: rows wr*32 .. +32
    const int wc   = wid & 1;    // 0..1: cols wc*32 .. +32
    const int l15  = lane & 15;
    const int quad = lane >> 4;

    const float sig = sigma[0];
    const float q  = 0.7213475204444817f / (sig * sig);
    const float q2 = 2.0f * q;

    const bool regmode = (int)blockIdx.x >= nA;
    int rowbase;
    float rowterm[2][4];
    short8 a[8];   // A fragments, tile-invariant: a[i*4+kk], i in {0,1}

    if (!regmode) {
        rowbase = blockIdx.x * TILE;
        // stage X tile into fragment-layout LDS; each thread converts a
        // quarter-row (32 elems)
        const int r_  = t >> 2;
        const int qtr = t & 3;
        const int grow = rowbase + r_;
        unsigned short* dstbase = &ldsA[0] + (r_ >> 4) * 2048 + (r_ & 15) * 8;
        float ss = 0.f;
        if (grow < N) {
            const float4* src = (const float4*)(X + (size_t)grow * 128 + qtr * 32);
            #pragma unroll
            for (int c = 0; c < 4; ++c) {
                float4 va = src[2 * c], vb = src[2 * c + 1];
                unsigned short h0 = f32_to_bf16(va.x), h1 = f32_to_bf16(va.y);
                unsigned short h2 = f32_to_bf16(va.z), h3 = f32_to_bf16(va.w);
                unsigned short h4 = f32_to_bf16(vb.x), h5 = f32_to_bf16(vb.y);
                unsigned short h6 = f32_to_bf16(vb.z), h7 = f32_to_bf16(vb.w);
                float f0 = bf16_to_f32(h0), f1 = bf16_to_f32(h1);
                float f2 = bf16_to_f32(h2), f3 = bf16_to_f32(h3);
                float f4 = bf16_to_f32(h4), f5 = bf16_to_f32(h5);
                float f6 = bf16_to_f32(h6), f7 = bf16_to_f32(h7);
                ss = fmaf(f0, f0, ss); ss = fmaf(f1, f1, ss);
                ss = fmaf(f2, f2, ss); ss = fmaf(f3, f3, ss);
                ss = fmaf(f4, f4, ss); ss = fmaf(f5, f5, ss);
                ss = fmaf(f6, f6, ss); ss = fmaf(f7, f7, ss);
                uint4 pk;
                pk.x = (uint32_t)h0 | ((uint32_t)h1 << 16);
                pk.y = (uint32_t)h2 | ((uint32_t)h3 << 16);
                pk.z = (uint32_t)h4 | ((uint32_t)h5 << 16);
                pk.w = (uint32_t)h6 | ((uint32_t)h7 << 16);
                *reinterpret_cast<uint4*>(dstbase + (qtr * 4 + c) * 128) = pk;
            }
        } else {
            uint4 z; z.x = z.y = z.z = z.w = 0u;
            #pragma unroll
            for (int c = 0; c < 4; ++c)
                *reinterpret_cast<uint4*>(dstbase + (qtr * 4 + c) * 128) = z;
        }
        a2p[r_][qtr] = ss;
        __syncthreads();
        #pragma unroll
        for (int i = 0; i < 2; ++i)
            #pragma unroll
            for (int r = 0; r < 4; ++r) {
                int rl = wr * 32 + i * 16 + quad * 4 + r;
                rowterm[i][r] = (a2p[rl][0] + a2p[rl][1] + a2p[rl][2] + a2p[rl][3]) * q;
            }
        // hoist A fragments: 8 ds_read_b128, once for the whole kernel.
        // Nothing overwrites ldsA afterwards -> no second barrier needed.
        const unsigned short* aLds = &ldsA[0] + (size_t)(wr * 2) * 2048 + lane * 8;
        #pragma unroll
        for (int i = 0; i < 2; ++i)
            #pragma unroll
            for (int kk = 0; kk < 4; ++kk)
                a[i * 4 + kk] = *reinterpret_cast<const short8*>(aLds + (size_t)i * 2048 + kk * 512);
    } else {
        const int b2 = (int)blockIdx.x - nA;
        rowbase = b2 * TILE;
        const unsigned short* aG = Bp + (size_t)(b2 * 8 + wr * 2) * 2048 + lane * 8;
        #pragma unroll
        for (int i = 0; i < 2; ++i)
            #pragma unroll
            for (int kk = 0; kk < 4; ++kk)
                a[i * 4 + kk] = *reinterpret_cast<const short8*>(aG + (size_t)i * 2048 + kk * 512);
        #pragma unroll
        for (int i = 0; i < 2; ++i)
            #pragma unroll
            for (int r = 0; r < 4; ++r)
                rowterm[i][r] = cw[rowbase + wr * 32 + i * 16 + quad * 4 + r].x;
    }

    float srow[2][4] = {};
    const float2* cwb = cw + wc * 32 + l15;
    // wave's B base: 16-col groups (mt*4 + wc*2 .. +1), fragment offset lane*8
    const unsigned short* bbase = Bp + (size_t)(wc * 2) * 2048 + lane * 8;

    // one compute step: 8 MFMA (K=128, one 16-col group) + exp2 epilogue
#define COMPUTE(B0, B1, B2, B3, CJ)                                          \
    do {                                                                     \
        f32x4 ac0 = (f32x4){0.f, 0.f, 0.f, 0.f};                             \
        f32x4 ac1 = (f32x4){0.f, 0.f, 0.f, 0.f};                             \
        ac0 = __builtin_amdgcn_mfma_f32_16x16x32_bf16(a[0], B0, ac0, 0, 0, 0); \
        ac1 = __builtin_amdgcn_mfma_f32_16x16x32_bf16(a[4], B0, ac1, 0, 0, 0); \
        ac0 = __builtin_amdgcn_mfma_f32_16x16x32_bf16(a[1], B1, ac0, 0, 0, 0); \
        ac1 = __builtin_amdgcn_mfma_f32_16x16x32_bf16(a[5], B1, ac1, 0, 0, 0); \
        ac0 = __builtin_amdgcn_mfma_f32_16x16x32_bf16(a[2], B2, ac0, 0, 0, 0); \
        ac1 = __builtin_amdgcn_mfma_f32_16x16x32_bf16(a[6], B2, ac1, 0, 0, 0); \
        ac0 = __builtin_amdgcn_mfma_f32_16x16x32_bf16(a[3], B3, ac0, 0, 0, 0); \
        ac1 = __builtin_amdgcn_mfma_f32_16x16x32_bf16(a[7], B3, ac1, 0, 0, 0); \
        _Pragma("unroll")                                                    \
        for (int r = 0; r < 4; ++r) {                                        \
            float u0 = fmaf(ac0[r], q2, -(rowterm[0][r] + CJ.x));            \
            float u1 = fmaf(ac1[r], q2, -(rowterm[1][r] + CJ.x));            \
            srow[0][r] = fmaf(__builtin_amdgcn_exp2f(u0), CJ.y, srow[0][r]); \
            srow[1][r] = fmaf(__builtin_amdgcn_exp2f(u1), CJ.y, srow[1][r]); \
        }                                                                    \
    } while (0)

    // software-pipelined, barrier-free m-loop: named 2-stage reg double
    // buffer; loads for step s+1 issued before compute of step s.
    short8 bA0, bA1, bA2, bA3, bB0, bB1, bB2, bB3;
    {
        const short8* p = (const short8*)bbase;   // (mt=0, j=0)
        bA0 = p[0];   // +0
        bA1 = *(const short8*)(bbase + 512);
        bA2 = *(const short8*)(bbase + 1024);
        bA3 = *(const short8*)(bbase + 1536);
    }
    for (int mt = 0; mt < nMt; ++mt) {
        float2 cj0 = cwb[(size_t)mt * 64];
        float2 cj1 = cwb[(size_t)mt * 64 + 16];
        const unsigned short* cur = bbase + (size_t)mt * 8192;

        // step j=0: prefetch (mt, j=1) into bB, compute bA
        bB0 = *(const short8*)(cur + 2048);
        bB1 = *(const short8*)(cur + 2048 + 512);
        bB2 = *(const short8*)(cur + 2048 + 1024);
        bB3 = *(const short8*)(cur + 2048 + 1536);
        COMPUTE(bA0, bA1, bA2, bA3, cj0);

        // step j=1: prefetch (mt+1, j=0) into bA (clamped on last iter to
        // avoid OOB; redundant load, branch-free), compute bB
        const unsigned short* nxt =
            bbase + (size_t)(mt + 1 < nMt ? mt + 1 : mt) * 8192;
        bA0 = *(const short8*)(nxt);
        bA1 = *(const short8*)(nxt + 512);
        bA2 = *(const short8*)(nxt + 1024);
        bA3 = *(const short8*)(nxt + 1536);
        COMPUTE(bB0, bB1, bB2, bB3, cj1);
    }
#undef COMPUTE

    // reduce srow over the 16 lanes sharing a row
    #pragma unroll
    for (int i = 0; i < 2; ++i) {
        #pragma unroll
        for (int r = 0; r < 4; ++r) {
            int rl = wr * 32 + i * 16 + quad * 4 + r;
            float v = srow[i][r];
            v += __shfl_xor(v, 1);
            v += __shfl_xor(v, 2);
            v += __shfl_xor(v, 4);
            v += __shfl_xor(v, 8);
            if (l15 == 0)
                predbuf[rl][wc] = v;
        }
    }
    __syncthreads();

    float contrib = 0.f;
    if (t < TILE) {
        int grow = rowbase + t;
        if (!regmode) {
            if (grow < N) {
                float pred = predbuf[t][0] + predbuf[t][1];
                preds_out[grow] = pred;
                float d = pred - Yv[grow];
                contrib = d * d;
            }
        } else {
            float pred = predbuf[t][0] + predbuf[t][1];
            contrib = alpha[grow] * pred;
        }
    }
    contrib += __shfl_xor(contrib, 1);
    contrib += __shfl_xor(contrib, 2);
    contrib += __shfl_xor(contrib, 4);
    contrib += __shfl_xor(contrib, 8);
    contrib += __shfl_xor(contrib, 16);
    contrib += __shfl_xor(contrib, 32);
    if (lane == 0 && wid < 2) atomicAdd(regmode ? (acc + 1) : (acc + 0), contrib);

    __syncthreads();   // all waves' atomics drained before counting
    if (t == 0) {
        __threadfence();
        unsigned int old = atomicAdd((unsigned int*)(acc + 2), 1u);
        if (old == (unsigned int)(nBlk - 1)) {
            float lv = atomicAdd(acc + 0, 0.0f);   // coherent read-back
            float rv = atomicAdd(acc + 1, 0.0f);
            out0[0] = lv / (float)N + __expf(-penalty[0]) * rv;
        }
    }
}

extern "C" void kernel_launch(void* const* d_in, const int* in_sizes, int n_in,
                              void* d_out, int out_size, void* d_ws, size_t ws_size,
                              hipStream_t stream) {
    const float* X       = (const float*)d_in[0];
    const float* Y       = (const float*)d_in[1];
    const float* centers = (const float*)d_in[2];
    const float* alpha   = (const float*)d_in[3];
    const float* sigma   = (const float*)d_in[4];
    const float* penalty = (const float*)d_in[5];
    float* out = (float*)d_out;

    const int N = in_sizes[1];   // Y is [N,1]
    const int M = in_sizes[3];   // alpha is [M,1]

    unsigned short* Bp = (unsigned short*)d_ws;                 // M*128 bf16 = M*256 B
    float2* cw = (float2*)((char*)d_ws + (size_t)M * 256);      // M*8 B
    float* acc = (float*)((char*)d_ws + (size_t)M * 264);       // loss, reg, counter

    prep_kernel<<<M / 16, 256, 0, stream>>>(centers, alpha, sigma, Bp, cw, acc);

    const int nA  = (N + TILE - 1) / TILE;
    const int nMt = M / BCOLS;            // 64-col B tiles
    const int nBlk = nA + M / TILE;
    fused_kernel<<<nBlk, 512, 0, stream>>>(X, N, Y, Bp, cw, alpha, sigma, penalty,
                                           nA, nMt, nBlk, out + 1, out, acc);
}

// Round 6
// 191.281 us; speedup vs baseline: 1.0355x; 1.0053x over previous
//
#include <hip/hip_runtime.h>
#include <stdint.h>

typedef short short8 __attribute__((ext_vector_type(8)));
typedef float f32x4 __attribute__((ext_vector_type(4)));

#define TILE 128          // A-tile rows per block (and K_MM reg-tile rows)
#define BCOLS 64          // B-tile cols per m-iteration

__device__ __forceinline__ unsigned short f32_to_bf16(float f) {
    uint32_t u = __builtin_bit_cast(uint32_t, f);
    u += 0x7FFFu + ((u >> 16) & 1u);   // RNE; data has no NaNs
    return (unsigned short)(u >> 16);
}
__device__ __forceinline__ float bf16_to_f32(unsigned short h) {
    return __builtin_bit_cast(float, (uint32_t)h << 16);
}

// async global->LDS DMA, 16 B per lane per issue (global_load_lds_dwordx4).
// HW semantics: per-lane global address; LDS dest = wave-uniform base + lane*16.
typedef const __attribute__((address_space(1))) uint32_t guint;
typedef __attribute__((address_space(3))) uint32_t luint;
__device__ __forceinline__ void dma16(const void* g, void* l) {
    __builtin_amdgcn_global_load_lds((guint*)g, (luint*)l, 16, 0, 0);
}

// Prep: centers fp32 -> bf16 in MFMA fragment layout, cw[m] = {||c||^2 * q, alpha[m]},
// and zero the accumulators (loss, reg, block counter).
// Fragment layout: element (row R, k) -> Bp[(R/16)*2048 + (k/8)*128 + (R%16)*8 + (k%8)]
__global__ void prep_kernel(const float* __restrict__ C,
                            const float* __restrict__ alpha,
                            const float* __restrict__ sigma,
                            unsigned short* __restrict__ Bp,
                            float2* __restrict__ cw,
                            float* __restrict__ acc)
{
    const int t = threadIdx.x;
    const int g = blockIdx.x;          // 16-row group
    const int r = t >> 4;              // row within group
    const int c16 = t & 15;            // 8-elem k-chunk
    const int R = g * 16 + r;

    if (g == 0 && t == 0) {
        acc[0] = 0.f; acc[1] = 0.f;
        ((unsigned int*)acc)[2] = 0u;
    }

    const float4* src = (const float4*)(C + (size_t)R * 128 + c16 * 8);
    float4 va = src[0], vb = src[1];
    unsigned short h[8];
    h[0] = f32_to_bf16(va.x); h[1] = f32_to_bf16(va.y);
    h[2] = f32_to_bf16(va.z); h[3] = f32_to_bf16(va.w);
    h[4] = f32_to_bf16(vb.x); h[5] = f32_to_bf16(vb.y);
    h[6] = f32_to_bf16(vb.z); h[7] = f32_to_bf16(vb.w);
    float ss = 0.f;
    #pragma unroll
    for (int k = 0; k < 8; ++k) {
        float f = bf16_to_f32(h[k]);
        ss = fmaf(f, f, ss);
    }
    uint4 pk;
    pk.x = (uint32_t)h[0] | ((uint32_t)h[1] << 16);
    pk.y = (uint32_t)h[2] | ((uint32_t)h[3] << 16);
    pk.z = (uint32_t)h[4] | ((uint32_t)h[5] << 16);
    pk.w = (uint32_t)h[6] | ((uint32_t)h[7] << 16);
    *reinterpret_cast<uint4*>(Bp + (size_t)g * 2048 + c16 * 128 + r * 8) = pk;

    ss += __shfl_xor(ss, 1);
    ss += __shfl_xor(ss, 2);
    ss += __shfl_xor(ss, 4);
    ss += __shfl_xor(ss, 8);
    if (c16 == 0) {
        float sig = sigma[0];
        float q = 0.7213475204444817f / (sig * sig);  // log2(e)/(2 sigma^2)
        cw[R] = make_float2(ss * q, alpha[R]);
    }
}

// Fused: blocks [0,nA) = preds + loss-sum; blocks [nA,nA+nMt) = K_MM regularizer.
//
// R7: R2's loop (76us, the schedule-axis local optimum: DMA double-buffer +
// one __syncthreads/iter; R3/R5/R6 proved hipcc defeats every source-level
// alternative) with a REGISTER-CHEAPER wave geometry to unlock residency.
// R2 ledger: 60 arch + 8 acc = 68 total > 64 -> 7 waves/SIMD -> 3 blocks/CU
// -> 768 slots < 798 blocks. Wall = total-iters x per-iter / capacity, so
// capacity 3->4 blocks/CU is worth ~25%.
// New mapping: 8 waves = 8 row-groups x 1 col-group; each wave owns 16 rows
// x all 64 cols of the 128x64 tile. a[8]->a[4] (-16 regs), rowterm[8]->[4]
// (-4), acc 8->4 (single MFMA chain; 32 waves/CU of TLP cover the chain
// latency), srow 8->16 (+8): ~52-56 arch + 4 acc <= 64 total -> 8 waves/SIMD
// -> 4 blocks/CU, whole grid in one round. Cost: each wave reads the whole
// 16KB B tile (2x LDS amplification, floor ~42us -- under target). Bonus:
// a row's cols all live in one wave -> predbuf needs no cross-wave add.
// (R4 lesson: nothing on the MFMA C-chain; rowterm stays in registers.)
__global__ __launch_bounds__(512, 4)
void fused_kernel(const float* __restrict__ X, int N,
                  const float* __restrict__ Yv,
                  const unsigned short* __restrict__ Bp,
                  const float2* __restrict__ cw,
                  const float* __restrict__ alpha,
                  const float* __restrict__ sigma,
                  const float* __restrict__ penalty,
                  int nA, int nMt, int nBlk,
                  float* __restrict__ preds_out,
                  float* __restrict__ out0,
                  float* __restrict__ acc)   // [0]=loss,[1]=reg,[2]=counter
{
    // ldsB[0] doubles as the A-staging buffer before the m-loop starts.
    __shared__ __align__(16) unsigned short ldsB[2][8192];  // 2 x 16 KB
    __shared__ float a2p[TILE][4];
    __shared__ float predbuf[TILE];

    const int t    = threadIdx.x;
    const int lane = t & 63;
    const int wid  = t >> 6;     // 0..7 = row group: rows wid*16 .. +16
    const int l15  = lane & 15;
    const int quad = lane >> 4;

    const float sig = sigma[0];
    const float q  = 0.7213475204444817f / (sig * sig);
    const float q2 = 2.0f * q;

    const bool regmode = (int)blockIdx.x >= nA;
    int rowbase;
    float rowterm[4];
    short8 a[4];   // A fragments (16 rows x K=128), tile-invariant

    if (!regmode) {
        rowbase = blockIdx.x * TILE;
        // stage X tile into fragment-layout LDS (whole 32KB of ldsB);
        // each thread converts a quarter-row (32 elems)
        const int r_  = t >> 2;
        const int qtr = t & 3;
        const int grow = rowbase + r_;
        unsigned short* dstbase = &ldsB[0][0] + (r_ >> 4) * 2048 + (r_ & 15) * 8;
        float ss = 0.f;
        if (grow < N) {
            const float4* src = (const float4*)(X + (size_t)grow * 128 + qtr * 32);
            #pragma unroll
            for (int c = 0; c < 4; ++c) {
                float4 va = src[2 * c], vb = src[2 * c + 1];
                unsigned short h0 = f32_to_bf16(va.x), h1 = f32_to_bf16(va.y);
                unsigned short h2 = f32_to_bf16(va.z), h3 = f32_to_bf16(va.w);
                unsigned short h4 = f32_to_bf16(vb.x), h5 = f32_to_bf16(vb.y);
                unsigned short h6 = f32_to_bf16(vb.z), h7 = f32_to_bf16(vb.w);
                float f0 = bf16_to_f32(h0), f1 = bf16_to_f32(h1);
                float f2 = bf16_to_f32(h2), f3 = bf16_to_f32(h3);
                float f4 = bf16_to_f32(h4), f5 = bf16_to_f32(h5);
                float f6 = bf16_to_f32(h6), f7 = bf16_to_f32(h7);
                ss = fmaf(f0, f0, ss); ss = fmaf(f1, f1, ss);
                ss = fmaf(f2, f2, ss); ss = fmaf(f3, f3, ss);
                ss = fmaf(f4, f4, ss); ss = fmaf(f5, f5, ss);
                ss = fmaf(f6, f6, ss); ss = fmaf(f7, f7, ss);
                uint4 pk;
                pk.x = (uint32_t)h0 | ((uint32_t)h1 << 16);
                pk.y = (uint32_t)h2 | ((uint32_t)h3 << 16);
                pk.z = (uint32_t)h4 | ((uint32_t)h5 << 16);
                pk.w = (uint32_t)h6 | ((uint32_t)h7 << 16);
                *reinterpret_cast<uint4*>(dstbase + (qtr * 4 + c) * 128) = pk;
            }
        } else {
            uint4 z; z.x = z.y = z.z = z.w = 0u;
            #pragma unroll
            for (int c = 0; c < 4; ++c)
                *reinterpret_cast<uint4*>(dstbase + (qtr * 4 + c) * 128) = z;
        }
        a2p[r_][qtr] = ss;
        __syncthreads();
        #pragma unroll
        for (int r = 0; r < 4; ++r) {
            int rl = wid * 16 + quad * 4 + r;
            rowterm[r] = (a2p[rl][0] + a2p[rl][1] + a2p[rl][2] + a2p[rl][3]) * q;
        }
        // hoist A fragments: 4 ds_read_b128, once for the whole kernel
        const unsigned short* aLds = &ldsB[0][0] + (size_t)wid * 2048 + lane * 8;
        #pragma unroll
        for (int kk = 0; kk < 4; ++kk)
            a[kk] = *reinterpret_cast<const short8*>(aLds + kk * 512);
        __syncthreads();   // all waves done reading A from ldsB before DMA overwrites
    } else {
        const int b2 = (int)blockIdx.x - nA;
        rowbase = b2 * TILE;
        const unsigned short* aG = Bp + (size_t)(b2 * 8 + wid) * 2048 + lane * 8;
        #pragma unroll
        for (int kk = 0; kk < 4; ++kk)
            a[kk] = *reinterpret_cast<const short8*>(aG + kk * 512);
        #pragma unroll
        for (int r = 0; r < 4; ++r)
            rowterm[r] = cw[rowbase + wid * 16 + quad * 4 + r].x;
    }

    float srow[4][4] = {};                  // [col group j][r]
    const float2* cwb = cw + l15;

    // this wave stages its 2 KB eighth of each 16KB tile: 2 x 1KB DMA issues
    const int ldq = wid * 1024 + lane * 8;   // element offset (shorts)

    // DMA tile 0 into ldsB[0]
    {
        const unsigned short* g = Bp + ldq;
        unsigned short* l = &ldsB[0][0] + ldq;
        #pragma unroll
        for (int k = 0; k < 2; ++k)
            dma16(g + k * 512, l + k * 512);
    }
    __syncthreads();   // vmcnt drain: tile 0 resident

    for (int mt = 0; mt < nMt; ++mt) {
        if (mt + 1 < nMt) {
            // fire-and-forget DMA of tile mt+1 into the other buffer;
            // drained by the barrier at the END of this iteration.
            const unsigned short* g = Bp + (size_t)(mt + 1) * 8192 + ldq;
            unsigned short* l = &ldsB[(mt + 1) & 1][0] + ldq;
            #pragma unroll
            for (int k = 0; k < 2; ++k)
                dma16(g + k * 512, l + k * 512);
        }

        // compute tile mt from LDS: 4 column groups of 16, K=128 each
        const unsigned short* bfr = &ldsB[mt & 1][0] + lane * 8;
        #pragma unroll
        for (int j = 0; j < 4; ++j) {
            float2 cj = cwb[(size_t)mt * 64 + j * 16];   // L2-hot col consts
            short8 b[4];
            #pragma unroll
            for (int kk = 0; kk < 4; ++kk)
                b[kk] = *reinterpret_cast<const short8*>(bfr + (size_t)j * 2048 + kk * 512);

            f32x4 acc4 = (f32x4){0.f, 0.f, 0.f, 0.f};
            #pragma unroll
            for (int kk = 0; kk < 4; ++kk)
                acc4 = __builtin_amdgcn_mfma_f32_16x16x32_bf16(a[kk], b[kk], acc4, 0, 0, 0);

            // epilogue: u = 2q*dot - (q*x2 + q*c2) <= ~0 ; srow += exp2(u)*alpha
            #pragma unroll
            for (int r = 0; r < 4; ++r) {
                float u = fmaf(acc4[r], q2, -(rowterm[r] + cj.x));
                float e = __builtin_amdgcn_exp2f(u);
                srow[j][r] = fmaf(e, cj.y, srow[j][r]);
            }
        }

        __syncthreads();   // drains DMA(mt+1); all waves done reading buf[mt&1]
    }

    // reduce: sum col groups in-register, then over the 16 lanes of a row
    #pragma unroll
    for (int r = 0; r < 4; ++r) {
        float v = (srow[0][r] + srow[1][r]) + (srow[2][r] + srow[3][r]);
        v += __shfl_xor(v, 1);
        v += __shfl_xor(v, 2);
        v += __shfl_xor(v, 4);
        v += __shfl_xor(v, 8);
        if (l15 == 0)
            predbuf[wid * 16 + quad * 4 + r] = v;
    }
    __syncthreads();

    float contrib = 0.f;
    if (t < TILE) {
        int grow = rowbase + t;
        if (!regmode) {
            if (grow < N) {
                float pred = predbuf[t];
                preds_out[grow] = pred;
                float d = pred - Yv[grow];
                contrib = d * d;
            }
        } else {
            contrib = alpha[grow] * predbuf[t];
        }
    }
    contrib += __shfl_xor(contrib, 1);
    contrib += __shfl_xor(contrib, 2);
    contrib += __shfl_xor(contrib, 4);
    contrib += __shfl_xor(contrib, 8);
    contrib += __shfl_xor(contrib, 16);
    contrib += __shfl_xor(contrib, 32);
    if (lane == 0 && wid < 2) atomicAdd(regmode ? (acc + 1) : (acc + 0), contrib);

    __syncthreads();   // all waves' atomics drained before counting
    if (t == 0) {
        __threadfence();
        unsigned int old = atomicAdd((unsigned int*)(acc + 2), 1u);
        if (old == (unsigned int)(nBlk - 1)) {
            float lv = atomicAdd(acc + 0, 0.0f);   // coherent read-back
            float rv = atomicAdd(acc + 1, 0.0f);
            out0[0] = lv / (float)N + __expf(-penalty[0]) * rv;
        }
    }
}

extern "C" void kernel_launch(void* const* d_in, const int* in_sizes, int n_in,
                              void* d_out, int out_size, void* d_ws, size_t ws_size,
                              hipStream_t stream) {
    const float* X       = (const float*)d_in[0];
    const float* Y       = (const float*)d_in[1];
    const float* centers = (const float*)d_in[2];
    const float* alpha   = (const float*)d_in[3];
    const float* sigma   = (const float*)d_in[4];
    const float* penalty = (const float*)d_in[5];
    float* out = (float*)d_out;

    const int N = in_sizes[1];   // Y is [N,1]
    const int M = in_sizes[3];   // alpha is [M,1]

    unsigned short* Bp = (unsigned short*)d_ws;                 // M*128 bf16 = M*256 B
    float2* cw = (float2*)((char*)d_ws + (size_t)M * 256);      // M*8 B
    float* acc = (float*)((char*)d_ws + (size_t)M * 264);       // loss, reg, counter

    prep_kernel<<<M / 16, 256, 0, stream>>>(centers, alpha, sigma, Bp, cw, acc);

    const int nA  = (N + TILE - 1) / TILE;
    const int nMt = M / BCOLS;            // 64-col B tiles
    const int nBlk = nA + M / TILE;
    fused_kernel<<<nBlk, 512, 0, stream>>>(X, N, Y, Bp, cw, alpha, sigma, penalty,
                                           nA, nMt, nBlk, out + 1, out, acc);
}

// Round 7
// 186.913 us; speedup vs baseline: 1.0597x; 1.0234x over previous
//
#include <hip/hip_runtime.h>
#include <stdint.h>

typedef short short8 __attribute__((ext_vector_type(8)));
typedef float f32x4 __attribute__((ext_vector_type(4)));

#define TILE 128          // A-tile rows per block (and K_MM reg-tile rows)
#define BCOLS 64          // B-tile cols per m-iteration

__device__ __forceinline__ unsigned short f32_to_bf16(float f) {
    uint32_t u = __builtin_bit_cast(uint32_t, f);
    u += 0x7FFFu + ((u >> 16) & 1u);   // RNE; data has no NaNs
    return (unsigned short)(u >> 16);
}
__device__ __forceinline__ float bf16_to_f32(unsigned short h) {
    return __builtin_bit_cast(float, (uint32_t)h << 16);
}

// async global->LDS DMA, 16 B per lane per issue (global_load_lds_dwordx4).
// HW semantics: per-lane global address; LDS dest = wave-uniform base + lane*16
// (ACTIVE lanes only).
typedef const __attribute__((address_space(1))) uint32_t guint;
typedef __attribute__((address_space(3))) uint32_t luint;
__device__ __forceinline__ void dma16(const void* g, void* l) {
    __builtin_amdgcn_global_load_lds((guint*)g, (luint*)l, 16, 0, 0);
}

// Prep: centers fp32 -> bf16 in MFMA fragment layout, cw[m] = {||c||^2 * q, alpha[m]},
// and zero the accumulators (loss, reg, block counter).
// Fragment layout: element (row R, k) -> Bp[(R/16)*2048 + (k/8)*128 + (R%16)*8 + (k%8)]
__global__ void prep_kernel(const float* __restrict__ C,
                            const float* __restrict__ alpha,
                            const float* __restrict__ sigma,
                            unsigned short* __restrict__ Bp,
                            float2* __restrict__ cw,
                            float* __restrict__ acc)
{
    const int t = threadIdx.x;
    const int g = blockIdx.x;          // 16-row group
    const int r = t >> 4;              // row within group
    const int c16 = t & 15;            // 8-elem k-chunk
    const int R = g * 16 + r;

    if (g == 0 && t == 0) {
        acc[0] = 0.f; acc[1] = 0.f;
        ((unsigned int*)acc)[2] = 0u;
    }

    const float4* src = (const float4*)(C + (size_t)R * 128 + c16 * 8);
    float4 va = src[0], vb = src[1];
    unsigned short h[8];
    h[0] = f32_to_bf16(va.x); h[1] = f32_to_bf16(va.y);
    h[2] = f32_to_bf16(va.z); h[3] = f32_to_bf16(va.w);
    h[4] = f32_to_bf16(vb.x); h[5] = f32_to_bf16(vb.y);
    h[6] = f32_to_bf16(vb.z); h[7] = f32_to_bf16(vb.w);
    float ss = 0.f;
    #pragma unroll
    for (int k = 0; k < 8; ++k) {
        float f = bf16_to_f32(h[k]);
        ss = fmaf(f, f, ss);
    }
    uint4 pk;
    pk.x = (uint32_t)h[0] | ((uint32_t)h[1] << 16);
    pk.y = (uint32_t)h[2] | ((uint32_t)h[3] << 16);
    pk.z = (uint32_t)h[4] | ((uint32_t)h[5] << 16);
    pk.w = (uint32_t)h[6] | ((uint32_t)h[7] << 16);
    *reinterpret_cast<uint4*>(Bp + (size_t)g * 2048 + c16 * 128 + r * 8) = pk;

    ss += __shfl_xor(ss, 1);
    ss += __shfl_xor(ss, 2);
    ss += __shfl_xor(ss, 4);
    ss += __shfl_xor(ss, 8);
    if (c16 == 0) {
        float sig = sigma[0];
        float q = 0.7213475204444817f / (sig * sig);  // log2(e)/(2 sigma^2)
        cw[R] = make_float2(ss * q, alpha[R]);
    }
}

// Fused: blocks [0,nA) = preds + loss-sum; blocks [nA,nA+nMt) = K_MM regularizer.
// 512 threads = 8 waves in a 4(row)x2(col) grid; each wave owns 32 rows x 32
// cols of the 128x64 tile. Loop structure = R2 verbatim (76us; R3/R5/R6
// proved every source-level schedule alternative loses to DMA-dbuf +
// __syncthreads on this compiler).
//
// Validated wall-time model: wall = per-block-work / (blocks/CU).
// R0->R2: 113->76 = 3/2 = 2->3 blocks/CU at fixed work. R7: work x2 (LDS
// amplification), capacity 4/3 -> 76*2/(4/3) = 114, measured 113-119.
// R2 residency: 60 arch + 8 acc = 68 > 64 total -> 7 waves/SIMD -> 3 blocks.
//
// R8 change: shave ~6 regs of demand WITHOUT touching compute geometry:
// per-tile column constants (cj) are DMA'd into LDS with the B tile (lane<32
// masked dma16, 512B/tile, all waves redundantly -- benign identical write;
// per-iter __syncthreads drains it, no vmcnt arithmetic, no asm). Removes
// cj[2] (4 regs live across j-loop) + cwb pointer (2) + in-loop global
// loads. cj ds_read_b64 feeds the EPILOGUE only -- not the MFMA C-operand
// chain (R4's failure). Target: ~62 total <= 64 -> 8 waves/SIMD -> 4
// blocks/CU -> 76 x 3/4 ~= 57us. No forced launch bounds (R1: forced-budget
// arch/acc split spills).
__global__ __launch_bounds__(512, 4)
void fused_kernel(const float* __restrict__ X, int N,
                  const float* __restrict__ Yv,
                  const unsigned short* __restrict__ Bp,
                  const float2* __restrict__ cw,
                  const float* __restrict__ alpha,
                  const float* __restrict__ sigma,
                  const float* __restrict__ penalty,
                  int nA, int nMt, int nBlk,
                  float* __restrict__ preds_out,
                  float* __restrict__ out0,
                  float* __restrict__ acc)   // [0]=loss,[1]=reg,[2]=counter
{
    // ldsB[0] doubles as the A-staging buffer before the m-loop starts.
    __shared__ __align__(16) unsigned short ldsB[2][8192];  // 2 x 16 KB
    __shared__ __align__(16) float2 cwLds[2][64];           // per-tile col consts
    __shared__ float a2p[TILE][4];
    __shared__ float predbuf[TILE][2];

    const int t    = threadIdx.x;
    const int lane = t & 63;
    const int wid  = t >> 6;     // 0..7
    const int wr   = wid >> 1;   // 0..3: rows wr*32 .. +32
    const int wc   = wid & 1;    // 0..1: cols wc*32 .. +32
    const int l15  = lane & 15;
    const int quad = lane >> 4;

    const float sig = sigma[0];
    const float q  = 0.7213475204444817f / (sig * sig);
    const float q2 = 2.0f * q;

    const bool regmode = (int)blockIdx.x >= nA;
    int rowbase;
    float rowterm[2][4];
    short8 a[8];   // A fragments, tile-invariant: a[i*4+kk], i in {0,1}

    if (!regmode) {
        rowbase = blockIdx.x * TILE;
        // stage X tile into fragment-layout LDS (whole 32KB of ldsB);
        // each thread converts a quarter-row (32 elems)
        const int r_  = t >> 2;
        const int qtr = t & 3;
        const int grow = rowbase + r_;
        unsigned short* dstbase = &ldsB[0][0] + (r_ >> 4) * 2048 + (r_ & 15) * 8;
        float ss = 0.f;
        if (grow < N) {
            const float4* src = (const float4*)(X + (size_t)grow * 128 + qtr * 32);
            #pragma unroll
            for (int c = 0; c < 4; ++c) {
                float4 va = src[2 * c], vb = src[2 * c + 1];
                unsigned short h0 = f32_to_bf16(va.x), h1 = f32_to_bf16(va.y);
                unsigned short h2 = f32_to_bf16(va.z), h3 = f32_to_bf16(va.w);
                unsigned short h4 = f32_to_bf16(vb.x), h5 = f32_to_bf16(vb.y);
                unsigned short h6 = f32_to_bf16(vb.z), h7 = f32_to_bf16(vb.w);
                float f0 = bf16_to_f32(h0), f1 = bf16_to_f32(h1);
                float f2 = bf16_to_f32(h2), f3 = bf16_to_f32(h3);
                float f4 = bf16_to_f32(h4), f5 = bf16_to_f32(h5);
                float f6 = bf16_to_f32(h6), f7 = bf16_to_f32(h7);
                ss = fmaf(f0, f0, ss); ss = fmaf(f1, f1, ss);
                ss = fmaf(f2, f2, ss); ss = fmaf(f3, f3, ss);
                ss = fmaf(f4, f4, ss); ss = fmaf(f5, f5, ss);
                ss = fmaf(f6, f6, ss); ss = fmaf(f7, f7, ss);
                uint4 pk;
                pk.x = (uint32_t)h0 | ((uint32_t)h1 << 16);
                pk.y = (uint32_t)h2 | ((uint32_t)h3 << 16);
                pk.z = (uint32_t)h4 | ((uint32_t)h5 << 16);
                pk.w = (uint32_t)h6 | ((uint32_t)h7 << 16);
                *reinterpret_cast<uint4*>(dstbase + (qtr * 4 + c) * 128) = pk;
            }
        } else {
            uint4 z; z.x = z.y = z.z = z.w = 0u;
            #pragma unroll
            for (int c = 0; c < 4; ++c)
                *reinterpret_cast<uint4*>(dstbase + (qtr * 4 + c) * 128) = z;
        }
        a2p[r_][qtr] = ss;
        __syncthreads();
        #pragma unroll
        for (int i = 0; i < 2; ++i)
            #pragma unroll
            for (int r = 0; r < 4; ++r) {
                int rl = wr * 32 + i * 16 + quad * 4 + r;
                rowterm[i][r] = (a2p[rl][0] + a2p[rl][1] + a2p[rl][2] + a2p[rl][3]) * q;
            }
        // hoist A fragments: 8 ds_read_b128, once for the whole kernel
        const unsigned short* aLds = &ldsB[0][0] + (size_t)(wr * 2) * 2048 + lane * 8;
        #pragma unroll
        for (int i = 0; i < 2; ++i)
            #pragma unroll
            for (int kk = 0; kk < 4; ++kk)
                a[i * 4 + kk] = *reinterpret_cast<const short8*>(aLds + (size_t)i * 2048 + kk * 512);
        __syncthreads();   // all waves done reading A from ldsB before DMA overwrites
    } else {
        const int b2 = (int)blockIdx.x - nA;
        rowbase = b2 * TILE;
        const unsigned short* aG = Bp + (size_t)(b2 * 8 + wr * 2) * 2048 + lane * 8;
        #pragma unroll
        for (int i = 0; i < 2; ++i)
            #pragma unroll
            for (int kk = 0; kk < 4; ++kk)
                a[i * 4 + kk] = *reinterpret_cast<const short8*>(aG + (size_t)i * 2048 + kk * 512);
        #pragma unroll
        for (int i = 0; i < 2; ++i)
            #pragma unroll
            for (int r = 0; r < 4; ++r)
                rowterm[i][r] = cw[rowbase + wr * 32 + i * 16 + quad * 4 + r].x;
    }

    float srow[2][4] = {};

    // this wave stages its 2 KB eighth of each 16KB tile: 2 x 1KB DMA issues
    const int ldq = wid * 1024 + lane * 8;   // element offset (shorts)

    // DMA tile 0 (B + col consts) into buffer 0
    {
        const unsigned short* g = Bp + ldq;
        unsigned short* l = &ldsB[0][0] + ldq;
        #pragma unroll
        for (int k = 0; k < 2; ++k)
            dma16(g + k * 512, l + k * 512);
        if (lane < 32)
            dma16(cw + (size_t)lane * 2, &cwLds[0][lane * 2]);
    }
    __syncthreads();   // vmcnt drain: tile 0 resident

    for (int mt = 0; mt < nMt; ++mt) {
        if (mt + 1 < nMt) {
            // fire-and-forget DMA of tile mt+1 into the other buffer;
            // drained by the barrier at the END of this iteration.
            const unsigned short* g = Bp + (size_t)(mt + 1) * 8192 + ldq;
            unsigned short* l = &ldsB[(mt + 1) & 1][0] + ldq;
            #pragma unroll
            for (int k = 0; k < 2; ++k)
                dma16(g + k * 512, l + k * 512);
            if (lane < 32)
                dma16(cw + (size_t)(mt + 1) * 64 + lane * 2,
                      &cwLds[(mt + 1) & 1][lane * 2]);
        }

        // compute tile mt from LDS: 2 column groups of 16, K=128 each
        const unsigned short* bfr = &ldsB[mt & 1][0] + (size_t)(wc * 2) * 2048 + lane * 8;
        const float2* cjl = &cwLds[mt & 1][wc * 32 + l15];
        #pragma unroll
        for (int j = 0; j < 2; ++j) {
            float2 cj = cjl[j * 16];   // ds_read_b64, broadcast across quads
            short8 b[4];
            #pragma unroll
            for (int kk = 0; kk < 4; ++kk)
                b[kk] = *reinterpret_cast<const short8*>(bfr + (size_t)j * 2048 + kk * 512);

            f32x4 acc4[2];
            #pragma unroll
            for (int i = 0; i < 2; ++i) acc4[i] = (f32x4){0.f, 0.f, 0.f, 0.f};
            #pragma unroll
            for (int kk = 0; kk < 4; ++kk)
                #pragma unroll
                for (int i = 0; i < 2; ++i)
                    acc4[i] = __builtin_amdgcn_mfma_f32_16x16x32_bf16(
                        a[i * 4 + kk], b[kk], acc4[i], 0, 0, 0);

            // epilogue: u = 2q*dot - (q*x2 + q*c2) <= ~0 ; srow += exp2(u)*alpha
            #pragma unroll
            for (int i = 0; i < 2; ++i) {
                #pragma unroll
                for (int r = 0; r < 4; ++r) {
                    float u = fmaf(acc4[i][r], q2, -(rowterm[i][r] + cj.x));
                    float e = __builtin_amdgcn_exp2f(u);
                    srow[i][r] = fmaf(e, cj.y, srow[i][r]);
                }
            }
        }

        __syncthreads();   // drains DMA(mt+1); all waves done reading buf[mt&1]
    }

    // reduce srow over the 16 lanes sharing a row
    #pragma unroll
    for (int i = 0; i < 2; ++i) {
        #pragma unroll
        for (int r = 0; r < 4; ++r) {
            int rl = wr * 32 + i * 16 + quad * 4 + r;
            float v = srow[i][r];
            v += __shfl_xor(v, 1);
            v += __shfl_xor(v, 2);
            v += __shfl_xor(v, 4);
            v += __shfl_xor(v, 8);
            if (l15 == 0)
                predbuf[rl][wc] = v;
        }
    }
    __syncthreads();

    float contrib = 0.f;
    if (t < TILE) {
        int grow = rowbase + t;
        if (!regmode) {
            if (grow < N) {
                float pred = predbuf[t][0] + predbuf[t][1];
                preds_out[grow] = pred;
                float d = pred - Yv[grow];
                contrib = d * d;
            }
        } else {
            float pred = predbuf[t][0] + predbuf[t][1];
            contrib = alpha[grow] * pred;
        }
    }
    contrib += __shfl_xor(contrib, 1);
    contrib += __shfl_xor(contrib, 2);
    contrib += __shfl_xor(contrib, 4);
    contrib += __shfl_xor(contrib, 8);
    contrib += __shfl_xor(contrib, 16);
    contrib += __shfl_xor(contrib, 32);
    if (lane == 0 && wid < 2) atomicAdd(regmode ? (acc + 1) : (acc + 0), contrib);

    __syncthreads();   // all waves' atomics drained before counting
    if (t == 0) {
        __threadfence();
        unsigned int old = atomicAdd((unsigned int*)(acc + 2), 1u);
        if (old == (unsigned int)(nBlk - 1)) {
            float lv = atomicAdd(acc + 0, 0.0f);   // coherent read-back
            float rv = atomicAdd(acc + 1, 0.0f);
            out0[0] = lv / (float)N + __expf(-penalty[0]) * rv;
        }
    }
}

extern "C" void kernel_launch(void* const* d_in, const int* in_sizes, int n_in,
                              void* d_out, int out_size, void* d_ws, size_t ws_size,
                              hipStream_t stream) {
    const float* X       = (const float*)d_in[0];
    const float* Y       = (const float*)d_in[1];
    const float* centers = (const float*)d_in[2];
    const float* alpha   = (const float*)d_in[3];
    const float* sigma   = (const float*)d_in[4];
    const float* penalty = (const float*)d_in[5];
    float* out = (float*)d_out;

    const int N = in_sizes[1];   // Y is [N,1]
    const int M = in_sizes[3];   // alpha is [M,1]

    unsigned short* Bp = (unsigned short*)d_ws;                 // M*128 bf16 = M*256 B
    float2* cw = (float2*)((char*)d_ws + (size_t)M * 256);      // M*8 B
    float* acc = (float*)((char*)d_ws + (size_t)M * 264);       // loss, reg, counter

    prep_kernel<<<M / 16, 256, 0, stream>>>(centers, alpha, sigma, Bp, cw, acc);

    const int nA  = (N + TILE - 1) / TILE;
    const int nMt = M / BCOLS;            // 64-col B tiles
    const int nBlk = nA + M / TILE;
    fused_kernel<<<nBlk, 512, 0, stream>>>(X, N, Y, Bp, cw, alpha, sigma, penalty,
                                           nA, nMt, nBlk, out + 1, out, acc);
}